// Round 1
// baseline (2311.228 us; speedup 1.0000x reference)
//
#include <hip/hip_runtime.h>

typedef _Float16 f16;
typedef _Float16 f16x8 __attribute__((ext_vector_type(8)));
typedef float f32x4 __attribute__((ext_vector_type(4)));

#define DIM 256
#define HID 512

// ws element offsets (f16 units)
#define WSO_W1  0
#define WSO_W2  131072
#define WSO_WC1 262144
#define WSO_WC2 278528
#define PACK_TOTAL 279552

// Pack weights into MFMA B-fragment order (16x16x32_f16):
// frag (kt,nt): lane l, elem j -> B[k = kt*32 + (l>>4)*8 + j][n = nt*16 + (l&15)]
__global__ void pack_weights(const float* __restrict__ W1, const float* __restrict__ W2,
                             const float* __restrict__ Wc1, const float* __restrict__ Wc2,
                             f16* __restrict__ ws) {
    int gid = blockIdx.x * 256 + threadIdx.x;
    if (gid >= PACK_TOTAL) return;
    if (gid < WSO_W2) {
        int g = gid;
        int j = g & 7, lane = (g >> 3) & 63, fi = g >> 9;
        int kt = fi >> 5, nt = fi & 31;                 // 8 x 32 frags
        int k = kt * 32 + ((lane >> 4) << 3) + j;       // 0..255
        int n = (nt << 4) + (lane & 15);                // 0..511
        ws[WSO_W1 + g] = (f16)W1[k * HID + n];
    } else if (gid < WSO_WC1) {
        int g = gid - WSO_W2;
        int j = g & 7, lane = (g >> 3) & 63, fi = g >> 9;
        int kt = fi >> 4, nt = fi & 15;                 // 16 x 16 frags
        int k = kt * 32 + ((lane >> 4) << 3) + j;       // 0..511
        int n = (nt << 4) + (lane & 15);                // 0..255
        ws[WSO_W2 + g] = (f16)W2[k * DIM + n];
    } else if (gid < WSO_WC2) {
        int g = gid - WSO_WC1;
        int j = g & 7, lane = (g >> 3) & 63, fi = g >> 9;
        int kt = fi >> 2, nt = fi & 3;                  // 8 x 4 frags
        int k = kt * 32 + ((lane >> 4) << 3) + j;       // 0..255
        int n = (nt << 4) + (lane & 15);                // 0..63
        ws[WSO_WC1 + g] = (f16)Wc1[k * 64 + n];
    } else {
        int g = gid - WSO_WC2;
        int j = g & 7, lane = (g >> 3) & 63, kt = g >> 9; // 2 frags
        int k = kt * 32 + ((lane >> 4) << 3) + j;        // 0..63
        int n = lane & 15;                               // pad cols 10..15 with 0
        ws[WSO_WC2 + g] = (n < 10) ? (f16)Wc2[k * 10 + n] : (f16)0.0f;
    }
}

__device__ __forceinline__ float tanh_fast(float x) {
    // tanh(x) = 1 - 2/(exp(2x)+1); exp via v_exp_f32, rcp via v_rcp_f32 (~1 ulp, plenty for f16 operands)
    float e = __expf(2.0f * x);
    return 1.0f - 2.0f * __builtin_amdgcn_rcpf(e + 1.0f);
}

// One evaluation of f(ys) = tanh(ys@W1+b1)@W2+b2 for this block's 16 rows.
// ycomb(ti,i) produces the stage input element for this thread's (ti,i) slot.
// Thread element layout (m2 accumulator layout):
//   row = (lane>>4)*4 + i ; col = wv*32 + ti*16 + (lane&15)
template <class F>
__device__ __forceinline__ void feval(F ycomb, float kv[2][4],
        f16* yst, f16* hbuf, const f16* __restrict__ ws,
        const f16x8 (&w2f)[2][16],
        int lane, int wv, const float b1c[4], const float b2c[2]) {
    const int cn  = lane & 15;
    const int rlo = (lane >> 4) << 2;
    const int koff = (lane >> 4) << 3;

    // ---- write stage input as swizzled f16 [16][256] ----
    #pragma unroll
    for (int ti = 0; ti < 2; ++ti) {
        #pragma unroll
        for (int i = 0; i < 4; ++i) {
            int row = rlo + i;
            int col = wv * 32 + ti * 16 + cn;
            int idx = (row << 8) + col;
            idx ^= (row & 7) << 3;               // bank-conflict swizzle (x2 bytes = <<4)
            yst[idx] = (f16)ycomb(ti, i);
        }
    }
    __syncthreads();   // BARRIER_A

    // ---- m1: h = ys @ W1, wave handles n-tiles {4wv..4wv+3}; W1 streamed from L2 ----
    f32x4 acc[4];
    #pragma unroll
    for (int q = 0; q < 4; ++q) acc[q] = (f32x4){0.f, 0.f, 0.f, 0.f};
    #pragma unroll
    for (int kt = 0; kt < 8; ++kt) {
        int aidx = ((cn << 8) + kt * 32 + koff) ^ ((cn & 7) << 3);
        f16x8 af = *(const f16x8*)(yst + aidx);
        #pragma unroll
        for (int q = 0; q < 4; ++q) {
            f16x8 wf = *(const f16x8*)(ws + WSO_W1 + (((kt * 32 + wv * 4 + q) << 6) + lane) * 8);
            acc[q] = __builtin_amdgcn_mfma_f32_16x16x32_f16(af, wf, acc[q], 0, 0, 0);
        }
    }
    // tanh + write swizzled f16 h [16][512]
    #pragma unroll
    for (int q = 0; q < 4; ++q) {
        int hcol = (wv * 4 + q) * 16 + cn;
        #pragma unroll
        for (int i = 0; i < 4; ++i) {
            float th = tanh_fast(acc[q][i] + b1c[q]);
            int row = rlo + i;
            int idx = (row << 9) + hcol;
            idx ^= (row & 7) << 3;
            hbuf[idx] = (f16)th;
        }
    }
    __syncthreads();   // BARRIER_B

    // ---- m2: k = tanh_h @ W2 + b2, W2 register-resident; wave n-tiles {2wv,2wv+1} ----
    f32x4 acc2[2];
    acc2[0] = (f32x4){0.f, 0.f, 0.f, 0.f};
    acc2[1] = (f32x4){0.f, 0.f, 0.f, 0.f};
    #pragma unroll
    for (int kt = 0; kt < 16; ++kt) {
        int aidx = ((cn << 9) + kt * 32 + koff) ^ ((cn & 7) << 3);
        f16x8 af = *(const f16x8*)(hbuf + aidx);
        #pragma unroll
        for (int ti = 0; ti < 2; ++ti)
            acc2[ti] = __builtin_amdgcn_mfma_f32_16x16x32_f16(af, w2f[ti][kt], acc2[ti], 0, 0, 0);
    }
    #pragma unroll
    for (int ti = 0; ti < 2; ++ti)
        #pragma unroll
        for (int i = 0; i < 4; ++i)
            kv[ti][i] = acc2[ti][i] + b2c[ti];
}

__launch_bounds__(512, 2)
__global__ void ode_main(const float* __restrict__ x0, const float* __restrict__ tg,
                         const float* __restrict__ b1, const float* __restrict__ b2,
                         const float* __restrict__ bc1, const float* __restrict__ bc2,
                         const f16* __restrict__ ws, float* __restrict__ out) {
    __shared__ f16 yst[16 * 256];    // 8 KB, swizzled stage input
    __shared__ f16 hbuf[16 * 512];   // 16 KB, swizzled tanh output
    __shared__ f16 h1buf[16 * 64];   // 2 KB, head hidden

    const int tid  = threadIdx.x;
    const int lane = tid & 63;
    const int wv   = tid >> 6;            // 0..7
    const int r0   = blockIdx.x * 16;
    const int cn   = lane & 15;
    const int rlo  = (lane >> 4) << 2;

    // y in registers, m2-acc layout: row = rlo+i, col = wv*32 + ti*16 + cn
    float y[2][4];
    #pragma unroll
    for (int ti = 0; ti < 2; ++ti)
        #pragma unroll
        for (int i = 0; i < 4; ++i)
            y[ti][i] = x0[(r0 + rlo + i) * DIM + wv * 32 + ti * 16 + cn];

    float b2c[2] = { b2[wv * 32 + cn], b2[wv * 32 + 16 + cn] };
    float b1c[4];
    #pragma unroll
    for (int q = 0; q < 4; ++q) b1c[q] = b1[(wv * 4 + q) * 16 + cn];

    // preload all of W2 into registers (2 n-tiles x 16 k-steps = 128 VGPRs/wave)
    f16x8 w2f[2][16];
    #pragma unroll
    for (int ti = 0; ti < 2; ++ti)
        #pragma unroll
        for (int kt = 0; kt < 16; ++kt)
            w2f[ti][kt] = *(const f16x8*)(ws + WSO_W2 + (((kt * 16 + (wv * 2 + ti)) << 6) + lane) * 8);

    float kk1[2][4], kk2[2][4], kk3[2][4], kk4[2][4], kk5[2][4], kk6[2][4];
    float dt = 0.f;

    for (int s = 0; s < 28; ++s) {
        if ((s & 3) == 0) { int iv = s >> 2; dt = (tg[iv + 1] - tg[iv]) * 0.25f; }

        feval([&](int ti, int i) { return y[ti][i]; },
              kk1, yst, hbuf, ws, w2f, lane, wv, b1c, b2c);
        feval([&](int ti, int i) { return y[ti][i] + dt * 0.2f * kk1[ti][i]; },
              kk2, yst, hbuf, ws, w2f, lane, wv, b1c, b2c);
        feval([&](int ti, int i) { return y[ti][i] + dt * (0.075f * kk1[ti][i] + 0.225f * kk2[ti][i]); },
              kk3, yst, hbuf, ws, w2f, lane, wv, b1c, b2c);
        feval([&](int ti, int i) { return y[ti][i] + dt * ((44.f/45.f) * kk1[ti][i] + (-56.f/15.f) * kk2[ti][i]
                                                          + (32.f/9.f) * kk3[ti][i]); },
              kk4, yst, hbuf, ws, w2f, lane, wv, b1c, b2c);
        feval([&](int ti, int i) { return y[ti][i] + dt * ((19372.f/6561.f) * kk1[ti][i] + (-25360.f/2187.f) * kk2[ti][i]
                                                          + (64448.f/6561.f) * kk3[ti][i] + (-212.f/729.f) * kk4[ti][i]); },
              kk5, yst, hbuf, ws, w2f, lane, wv, b1c, b2c);
        feval([&](int ti, int i) { return y[ti][i] + dt * ((9017.f/3168.f) * kk1[ti][i] + (-355.f/33.f) * kk2[ti][i]
                                                          + (46732.f/5247.f) * kk3[ti][i] + (49.f/176.f) * kk4[ti][i]
                                                          + (-5103.f/18656.f) * kk5[ti][i]); },
              kk6, yst, hbuf, ws, w2f, lane, wv, b1c, b2c);

        #pragma unroll
        for (int ti = 0; ti < 2; ++ti)
            #pragma unroll
            for (int i = 0; i < 4; ++i)
                y[ti][i] += dt * ((35.f/384.f)   * kk1[ti][i] + (500.f/1113.f) * kk3[ti][i]
                                + (125.f/192.f)  * kk4[ti][i] + (-2187.f/6784.f) * kk5[ti][i]
                                + (11.f/84.f)    * kk6[ti][i]);
    }

    // ---------------- classifier head ----------------
    // write final y as swizzled f16 into yst
    #pragma unroll
    for (int ti = 0; ti < 2; ++ti)
        #pragma unroll
        for (int i = 0; i < 4; ++i) {
            int row = rlo + i;
            int col = wv * 32 + ti * 16 + cn;
            int idx = (row << 8) + col;
            idx ^= (row & 7) << 3;
            yst[idx] = (f16)y[ti][i];
        }
    __syncthreads();

    // h1 = relu(y @ Wc1 + bc1): waves 0..3 each do one 16-col tile
    if (wv < 4) {
        f32x4 acc = (f32x4){0.f, 0.f, 0.f, 0.f};
        const int koff = (lane >> 4) << 3;
        #pragma unroll
        for (int kt = 0; kt < 8; ++kt) {
            int aidx = ((cn << 8) + kt * 32 + koff) ^ ((cn & 7) << 3);
            f16x8 af = *(const f16x8*)(yst + aidx);
            f16x8 wf = *(const f16x8*)(ws + WSO_WC1 + (((kt * 4 + wv) << 6) + lane) * 8);
            acc = __builtin_amdgcn_mfma_f32_16x16x32_f16(af, wf, acc, 0, 0, 0);
        }
        float bb = bc1[wv * 16 + cn];
        #pragma unroll
        for (int i = 0; i < 4; ++i) {
            float v = fmaxf(acc[i] + bb, 0.f);
            int row = rlo + i;
            int col = wv * 16 + cn;
            int idx = (row << 6) + col;
            idx ^= (row & 7) << 3;
            h1buf[idx] = (f16)v;
        }
    }
    __syncthreads();

    // logits = h1 @ Wc2 + bc2 (cols 10..15 of packed Wc2 are zero): wave 0 only
    if (wv == 0) {
        f32x4 acc = (f32x4){0.f, 0.f, 0.f, 0.f};
        const int koff = (lane >> 4) << 3;
        #pragma unroll
        for (int kt = 0; kt < 2; ++kt) {
            int aidx = ((cn << 6) + kt * 32 + koff) ^ ((cn & 7) << 3);
            f16x8 af = *(const f16x8*)(h1buf + aidx);
            f16x8 wf = *(const f16x8*)(ws + WSO_WC2 + ((kt << 6) + lane) * 8);
            acc = __builtin_amdgcn_mfma_f32_16x16x32_f16(af, wf, acc, 0, 0, 0);
        }
        if (cn < 10) {
            float bb = bc2[cn];
            #pragma unroll
            for (int i = 0; i < 4; ++i)
                out[(r0 + rlo + i) * 10 + cn] = acc[i] + bb;
        }
    }
}

extern "C" void kernel_launch(void* const* d_in, const int* in_sizes, int n_in,
                              void* d_out, int out_size, void* d_ws, size_t ws_size,
                              hipStream_t stream) {
    const float* x0  = (const float*)d_in[0];
    const float* tg  = (const float*)d_in[1];
    const float* W1  = (const float*)d_in[2];
    const float* b1  = (const float*)d_in[3];
    const float* W2  = (const float*)d_in[4];
    const float* b2  = (const float*)d_in[5];
    const float* Wc1 = (const float*)d_in[6];
    const float* bc1 = (const float*)d_in[7];
    const float* Wc2 = (const float*)d_in[8];
    const float* bc2 = (const float*)d_in[9];
    f16* ws = (f16*)d_ws;
    float* out = (float*)d_out;

    pack_weights<<<(PACK_TOTAL + 255) / 256, 256, 0, stream>>>(W1, W2, Wc1, Wc2, ws);
    ode_main<<<128, 512, 0, stream>>>(x0, tg, b1, b2, bc1, bc2, ws, out);
}

// Round 2
// 2285.152 us; speedup vs baseline: 1.0114x; 1.0114x over previous
//
#include <hip/hip_runtime.h>

typedef _Float16 f16;
typedef _Float16 f16x8 __attribute__((ext_vector_type(8)));
typedef float f32x4 __attribute__((ext_vector_type(4)));

#define DIM 256
#define HID 512

// ws element offsets (f16 units)
#define WSO_W1  0
#define WSO_W2  131072
#define WSO_WC1 262144
#define WSO_WC2 278528
#define PACK_TOTAL 279552

// Pack weights into MFMA B-fragment order (16x16x32_f16):
// frag (kt,nt): lane l, elem j -> B[k = kt*32 + (l>>4)*8 + j][n = nt*16 + (l&15)]
__global__ void pack_weights(const float* __restrict__ W1, const float* __restrict__ W2,
                             const float* __restrict__ Wc1, const float* __restrict__ Wc2,
                             f16* __restrict__ ws) {
    int gid = blockIdx.x * 256 + threadIdx.x;
    if (gid >= PACK_TOTAL) return;
    if (gid < WSO_W2) {
        int g = gid;
        int j = g & 7, lane = (g >> 3) & 63, fi = g >> 9;
        int kt = fi >> 5, nt = fi & 31;                 // 8 x 32 frags
        int k = kt * 32 + ((lane >> 4) << 3) + j;       // 0..255
        int n = (nt << 4) + (lane & 15);                // 0..511
        ws[WSO_W1 + g] = (f16)W1[k * HID + n];
    } else if (gid < WSO_WC1) {
        int g = gid - WSO_W2;
        int j = g & 7, lane = (g >> 3) & 63, fi = g >> 9;
        int kt = fi >> 4, nt = fi & 15;                 // 16 x 16 frags
        int k = kt * 32 + ((lane >> 4) << 3) + j;       // 0..511
        int n = (nt << 4) + (lane & 15);                // 0..255
        ws[WSO_W2 + g] = (f16)W2[k * DIM + n];
    } else if (gid < WSO_WC2) {
        int g = gid - WSO_WC1;
        int j = g & 7, lane = (g >> 3) & 63, fi = g >> 9;
        int kt = fi >> 2, nt = fi & 3;                  // 8 x 4 frags
        int k = kt * 32 + ((lane >> 4) << 3) + j;       // 0..255
        int n = (nt << 4) + (lane & 15);                // 0..63
        ws[WSO_WC1 + g] = (f16)Wc1[k * 64 + n];
    } else {
        int g = gid - WSO_WC2;
        int j = g & 7, lane = (g >> 3) & 63, kt = g >> 9; // 2 frags
        int k = kt * 32 + ((lane >> 4) << 3) + j;        // 0..63
        int n = lane & 15;                               // pad cols 10..15 with 0
        ws[WSO_WC2 + g] = (n < 10) ? (f16)Wc2[k * 10 + n] : (f16)0.0f;
    }
}

__device__ __forceinline__ float tanh_fast(float x) {
    // tanh(x) = 1 - 2/(exp(2x)+1); exp via v_exp_f32, rcp via v_rcp_f32
    float e = __expf(2.0f * x);
    return 1.0f - 2.0f * __builtin_amdgcn_rcpf(e + 1.0f);
}

// One evaluation of f(ys) = tanh(ys@W1+b1)@W2+b2 for this block's 16 rows.
// All weights register-resident (w1f, w2f); only LDS traffic per eval.
// Thread element layout (m2 accumulator layout):
//   row = (lane>>4)*4 + i ; col = wv*32 + ti*16 + (lane&15)
template <class F>
__device__ __forceinline__ void feval(F ycomb, float kv[2][4],
        f16* yst, f16* hbuf,
        const f16x8 (&w1f)[4][8], const f16x8 (&w2f)[2][16],
        int lane, int wv, const float b1c[4], const float b2c[2]) {
    const int cn  = lane & 15;
    const int rlo = (lane >> 4) << 2;
    const int koff = (lane >> 4) << 3;

    // ---- write stage input as swizzled f16 [16][256] ----
    #pragma unroll
    for (int ti = 0; ti < 2; ++ti) {
        #pragma unroll
        for (int i = 0; i < 4; ++i) {
            int row = rlo + i;
            int col = wv * 32 + ti * 16 + cn;
            int idx = (row << 8) + col;
            idx ^= (row & 7) << 3;               // bank-conflict swizzle
            yst[idx] = (f16)ycomb(ti, i);
        }
    }
    __syncthreads();   // BARRIER_A

    // ---- m1: h = ys @ W1, wave handles n-tiles {4wv..4wv+3}; W1 in registers ----
    f32x4 acc[4];
    #pragma unroll
    for (int q = 0; q < 4; ++q) acc[q] = (f32x4){0.f, 0.f, 0.f, 0.f};
    #pragma unroll
    for (int kt = 0; kt < 8; ++kt) {
        int aidx = ((cn << 8) + kt * 32 + koff) ^ ((cn & 7) << 3);
        f16x8 af = *(const f16x8*)(yst + aidx);
        #pragma unroll
        for (int q = 0; q < 4; ++q)
            acc[q] = __builtin_amdgcn_mfma_f32_16x16x32_f16(af, w1f[q][kt], acc[q], 0, 0, 0);
    }
    // tanh + write swizzled f16 h [16][512]
    #pragma unroll
    for (int q = 0; q < 4; ++q) {
        int hcol = (wv * 4 + q) * 16 + cn;
        #pragma unroll
        for (int i = 0; i < 4; ++i) {
            float th = tanh_fast(acc[q][i] + b1c[q]);
            int row = rlo + i;
            int idx = (row << 9) + hcol;
            idx ^= (row & 7) << 3;
            hbuf[idx] = (f16)th;
        }
    }
    __syncthreads();   // BARRIER_B

    // ---- m2: k = tanh_h @ W2 + b2, W2 register-resident; wave n-tiles {2wv,2wv+1} ----
    f32x4 acc2[2];
    acc2[0] = (f32x4){0.f, 0.f, 0.f, 0.f};
    acc2[1] = (f32x4){0.f, 0.f, 0.f, 0.f};
    #pragma unroll
    for (int kt = 0; kt < 16; ++kt) {
        int aidx = ((cn << 9) + kt * 32 + koff) ^ ((cn & 7) << 3);
        f16x8 af = *(const f16x8*)(hbuf + aidx);
        #pragma unroll
        for (int ti = 0; ti < 2; ++ti)
            acc2[ti] = __builtin_amdgcn_mfma_f32_16x16x32_f16(af, w2f[ti][kt], acc2[ti], 0, 0, 0);
    }
    #pragma unroll
    for (int ti = 0; ti < 2; ++ti)
        #pragma unroll
        for (int i = 0; i < 4; ++i)
            kv[ti][i] = acc2[ti][i] + b2c[ti];
}

__launch_bounds__(512, 1)
__global__ void ode_main(const float* __restrict__ x0, const float* __restrict__ tg,
                         const float* __restrict__ b1, const float* __restrict__ b2,
                         const float* __restrict__ bc1, const float* __restrict__ bc2,
                         const f16* __restrict__ ws, float* __restrict__ out) {
    __shared__ f16 yst[16 * 256];    // 8 KB, swizzled stage input
    __shared__ f16 hbuf[16 * 512];   // 16 KB, swizzled tanh output
    __shared__ f16 h1buf[16 * 64];   // 2 KB, head hidden

    const int tid  = threadIdx.x;
    const int lane = tid & 63;
    const int wv   = tid >> 6;            // 0..7
    const int r0   = blockIdx.x * 16;
    const int cn   = lane & 15;
    const int rlo  = (lane >> 4) << 2;

    // y in registers, m2-acc layout: row = rlo+i, col = wv*32 + ti*16 + cn
    float y[2][4];
    #pragma unroll
    for (int ti = 0; ti < 2; ++ti)
        #pragma unroll
        for (int i = 0; i < 4; ++i)
            y[ti][i] = x0[(r0 + rlo + i) * DIM + wv * 32 + ti * 16 + cn];

    float b2c[2] = { b2[wv * 32 + cn], b2[wv * 32 + 16 + cn] };
    float b1c[4];
    #pragma unroll
    for (int q = 0; q < 4; ++q) b1c[q] = b1[(wv * 4 + q) * 16 + cn];

    // preload ALL weight fragments this wave ever needs into registers:
    // W1: 4 n-tiles x 8 k-steps = 128 regs; W2: 2 n-tiles x 16 k-steps = 128 regs
    f16x8 w1f[4][8];
    #pragma unroll
    for (int q = 0; q < 4; ++q)
        #pragma unroll
        for (int kt = 0; kt < 8; ++kt)
            w1f[q][kt] = *(const f16x8*)(ws + WSO_W1 + (((kt * 32 + wv * 4 + q) << 6) + lane) * 8);

    f16x8 w2f[2][16];
    #pragma unroll
    for (int ti = 0; ti < 2; ++ti)
        #pragma unroll
        for (int kt = 0; kt < 16; ++kt)
            w2f[ti][kt] = *(const f16x8*)(ws + WSO_W2 + (((kt * 16 + (wv * 2 + ti)) << 6) + lane) * 8);

    float kk1[2][4], kk2[2][4], kk3[2][4], kk4[2][4], kk5[2][4], kk6[2][4];
    float dt = 0.f;

    for (int s = 0; s < 28; ++s) {
        if ((s & 3) == 0) { int iv = s >> 2; dt = (tg[iv + 1] - tg[iv]) * 0.25f; }

        feval([&](int ti, int i) { return y[ti][i]; },
              kk1, yst, hbuf, w1f, w2f, lane, wv, b1c, b2c);
        feval([&](int ti, int i) { return y[ti][i] + dt * 0.2f * kk1[ti][i]; },
              kk2, yst, hbuf, w1f, w2f, lane, wv, b1c, b2c);
        feval([&](int ti, int i) { return y[ti][i] + dt * (0.075f * kk1[ti][i] + 0.225f * kk2[ti][i]); },
              kk3, yst, hbuf, w1f, w2f, lane, wv, b1c, b2c);
        feval([&](int ti, int i) { return y[ti][i] + dt * ((44.f/45.f) * kk1[ti][i] + (-56.f/15.f) * kk2[ti][i]
                                                          + (32.f/9.f) * kk3[ti][i]); },
              kk4, yst, hbuf, w1f, w2f, lane, wv, b1c, b2c);
        feval([&](int ti, int i) { return y[ti][i] + dt * ((19372.f/6561.f) * kk1[ti][i] + (-25360.f/2187.f) * kk2[ti][i]
                                                          + (64448.f/6561.f) * kk3[ti][i] + (-212.f/729.f) * kk4[ti][i]); },
              kk5, yst, hbuf, w1f, w2f, lane, wv, b1c, b2c);
        feval([&](int ti, int i) { return y[ti][i] + dt * ((9017.f/3168.f) * kk1[ti][i] + (-355.f/33.f) * kk2[ti][i]
                                                          + (46732.f/5247.f) * kk3[ti][i] + (49.f/176.f) * kk4[ti][i]
                                                          + (-5103.f/18656.f) * kk5[ti][i]); },
              kk6, yst, hbuf, w1f, w2f, lane, wv, b1c, b2c);

        #pragma unroll
        for (int ti = 0; ti < 2; ++ti)
            #pragma unroll
            for (int i = 0; i < 4; ++i)
                y[ti][i] += dt * ((35.f/384.f)   * kk1[ti][i] + (500.f/1113.f) * kk3[ti][i]
                                + (125.f/192.f)  * kk4[ti][i] + (-2187.f/6784.f) * kk5[ti][i]
                                + (11.f/84.f)    * kk6[ti][i]);
    }

    // ---------------- classifier head ----------------
    // write final y as swizzled f16 into yst
    #pragma unroll
    for (int ti = 0; ti < 2; ++ti)
        #pragma unroll
        for (int i = 0; i < 4; ++i) {
            int row = rlo + i;
            int col = wv * 32 + ti * 16 + cn;
            int idx = (row << 8) + col;
            idx ^= (row & 7) << 3;
            yst[idx] = (f16)y[ti][i];
        }
    __syncthreads();

    // h1 = relu(y @ Wc1 + bc1): waves 0..3 each do one 16-col tile
    if (wv < 4) {
        f32x4 acc = (f32x4){0.f, 0.f, 0.f, 0.f};
        const int koff = (lane >> 4) << 3;
        #pragma unroll
        for (int kt = 0; kt < 8; ++kt) {
            int aidx = ((cn << 8) + kt * 32 + koff) ^ ((cn & 7) << 3);
            f16x8 af = *(const f16x8*)(yst + aidx);
            f16x8 wf = *(const f16x8*)(ws + WSO_WC1 + (((kt * 4 + wv) << 6) + lane) * 8);
            acc = __builtin_amdgcn_mfma_f32_16x16x32_f16(af, wf, acc, 0, 0, 0);
        }
        float bb = bc1[wv * 16 + cn];
        #pragma unroll
        for (int i = 0; i < 4; ++i) {
            float v = fmaxf(acc[i] + bb, 0.f);
            int row = rlo + i;
            int col = wv * 16 + cn;
            int idx = (row << 6) + col;
            idx ^= (row & 7) << 3;
            h1buf[idx] = (f16)v;
        }
    }
    __syncthreads();

    // logits = h1 @ Wc2 + bc2 (cols 10..15 of packed Wc2 are zero): wave 0 only
    if (wv == 0) {
        f32x4 acc = (f32x4){0.f, 0.f, 0.f, 0.f};
        const int koff = (lane >> 4) << 3;
        #pragma unroll
        for (int kt = 0; kt < 2; ++kt) {
            int aidx = ((cn << 6) + kt * 32 + koff) ^ ((cn & 7) << 3);
            f16x8 af = *(const f16x8*)(h1buf + aidx);
            f16x8 wf = *(const f16x8*)(ws + WSO_WC2 + ((kt << 6) + lane) * 8);
            acc = __builtin_amdgcn_mfma_f32_16x16x32_f16(af, wf, acc, 0, 0, 0);
        }
        if (cn < 10) {
            float bb = bc2[cn];
            #pragma unroll
            for (int i = 0; i < 4; ++i)
                out[(r0 + rlo + i) * 10 + cn] = acc[i] + bb;
        }
    }
}

extern "C" void kernel_launch(void* const* d_in, const int* in_sizes, int n_in,
                              void* d_out, int out_size, void* d_ws, size_t ws_size,
                              hipStream_t stream) {
    const float* x0  = (const float*)d_in[0];
    const float* tg  = (const float*)d_in[1];
    const float* W1  = (const float*)d_in[2];
    const float* b1  = (const float*)d_in[3];
    const float* W2  = (const float*)d_in[4];
    const float* b2  = (const float*)d_in[5];
    const float* Wc1 = (const float*)d_in[6];
    const float* bc1 = (const float*)d_in[7];
    const float* Wc2 = (const float*)d_in[8];
    const float* bc2 = (const float*)d_in[9];
    f16* ws = (f16*)d_ws;
    float* out = (float*)d_out;

    pack_weights<<<(PACK_TOTAL + 255) / 256, 256, 0, stream>>>(W1, W2, Wc1, Wc2, ws);
    ode_main<<<128, 512, 0, stream>>>(x0, tg, b1, b2, bc1, bc2, ws, out);
}

// Round 3
// 2099.497 us; speedup vs baseline: 1.1008x; 1.0884x over previous
//
#include <hip/hip_runtime.h>

typedef _Float16 f16;
typedef _Float16 f16x8 __attribute__((ext_vector_type(8)));
typedef float f32x4 __attribute__((ext_vector_type(4)));

#define DIM 256
#define HID 512

// ws element offsets (f16 units)
#define WSO_W1  0
#define WSO_W2  131072
#define WSO_WC1 262144
#define WSO_WC2 278528
#define PACK_TOTAL 279552

// LDS byte layout (dynamic smem): W1 kt4..7 frags | yst | hbuf
#define LDS_W1   0
#define LDS_YST  131072
#define LDS_HB   139264
#define SMEM_BYTES 155648   // 152 KB -> 1 block/CU

#define MFMA(a, b, c) __builtin_amdgcn_mfma_f32_16x16x32_f16(a, b, c, 0, 0, 0)

// Pack weights into MFMA B-fragment order (16x16x32_f16):
// frag (kt,nt): lane l, elem j -> B[k = kt*32 + (l>>4)*8 + j][n = nt*16 + (l&15)]
__global__ void pack_weights(const float* __restrict__ W1, const float* __restrict__ W2,
                             const float* __restrict__ Wc1, const float* __restrict__ Wc2,
                             f16* __restrict__ ws) {
    int gid = blockIdx.x * 256 + threadIdx.x;
    if (gid >= PACK_TOTAL) return;
    if (gid < WSO_W2) {
        int g = gid;
        int j = g & 7, lane = (g >> 3) & 63, fi = g >> 9;
        int kt = fi >> 5, nt = fi & 31;                 // 8 x 32 frags
        int k = kt * 32 + ((lane >> 4) << 3) + j;
        int n = (nt << 4) + (lane & 15);
        ws[WSO_W1 + g] = (f16)W1[k * HID + n];
    } else if (gid < WSO_WC1) {
        int g = gid - WSO_W2;
        int j = g & 7, lane = (g >> 3) & 63, fi = g >> 9;
        int kt = fi >> 4, nt = fi & 15;                 // 16 x 16 frags
        int k = kt * 32 + ((lane >> 4) << 3) + j;
        int n = (nt << 4) + (lane & 15);
        ws[WSO_W2 + g] = (f16)W2[k * DIM + n];
    } else if (gid < WSO_WC2) {
        int g = gid - WSO_WC1;
        int j = g & 7, lane = (g >> 3) & 63, fi = g >> 9;
        int kt = fi >> 2, nt = fi & 3;                  // 8 x 4 frags
        int k = kt * 32 + ((lane >> 4) << 3) + j;
        int n = (nt << 4) + (lane & 15);
        ws[WSO_WC1 + g] = (f16)Wc1[k * 64 + n];
    } else {
        int g = gid - WSO_WC2;
        int j = g & 7, lane = (g >> 3) & 63, kt = g >> 9; // 2 frags
        int k = kt * 32 + ((lane >> 4) << 3) + j;
        int n = lane & 15;
        ws[WSO_WC2 + g] = (n < 10) ? (f16)Wc2[k * 10 + n] : (f16)0.0f;
    }
}

__device__ __forceinline__ float tanh_fast(float x) {
    float e = __expf(2.0f * x);
    return 1.0f - 2.0f * __builtin_amdgcn_rcpf(e + 1.0f);
}

// f(ys) = tanh(ys@W1+b1)@W2+b2 for this block's 16 rows. 4 waves.
// Wave w: m1 n-tiles w*8..w*8+7 (HID), m2 n-tiles w*4..w*4+3 (DIM).
// Thread slot layout (m2 acc layout): row = (lane>>4)*4+i, col = (w*4+t)*16+(lane&15)
template <class F>
__device__ __forceinline__ void feval(F ycomb, float kv[4][4],
        const f16* __restrict__ ws, const f16* w1lds, f16* yst, f16* hbuf,
        const f16x8 (&w1r)[8][3], const f16x8 (&w2r)[4][11],
        int lane, int w, const float b1c[8], const float b2c[4]) {
    const int cn   = lane & 15;
    const int rlo  = (lane >> 4) << 2;
    const int koff = (lane >> 4) << 3;

    // stream W1 kt3 frags from L2 (issued early; used mid-m1)
    f16x8 w1s[8];
    #pragma unroll
    for (int q = 0; q < 8; ++q)
        w1s[q] = *(const f16x8*)(ws + WSO_W1 + (((3 * 32 + w * 8 + q) << 6) + lane) * 8);

    // ---- write stage input, swizzled f16 [16][256] ----
    #pragma unroll
    for (int t = 0; t < 4; ++t)
        #pragma unroll
        for (int i = 0; i < 4; ++i) {
            int row = rlo + i;
            int col = ((w * 4 + t) << 4) + cn;
            int idx = ((row << 8) + col) ^ ((row & 7) << 3);
            yst[idx] = (f16)ycomb(t, i);
        }
    __syncthreads();   // BARRIER_A

    // ---- m1: h = ys @ W1 ; W1 from regs (kt0-2) / stream (kt3) / LDS (kt4-7) ----
    f32x4 acc[8];
    #pragma unroll
    for (int q = 0; q < 8; ++q) acc[q] = (f32x4){0.f, 0.f, 0.f, 0.f};
    #pragma unroll
    for (int kt = 0; kt < 8; ++kt) {
        int aidx = ((cn << 8) + kt * 32 + koff) ^ ((cn & 7) << 3);
        f16x8 af = *(const f16x8*)(yst + aidx);
        #pragma unroll
        for (int q = 0; q < 8; ++q) {
            f16x8 wf;
            if (kt < 3)       wf = w1r[q][kt];
            else if (kt == 3) wf = w1s[q];
            else              wf = *(const f16x8*)(w1lds + (((kt - 4) * 32 + w * 8 + q) << 9) + lane * 8);
            acc[q] = MFMA(af, wf, acc[q]);
        }
    }
    // tanh -> swizzled hbuf [16][512]
    #pragma unroll
    for (int q = 0; q < 8; ++q) {
        int hcol = ((w * 8 + q) << 4) + cn;
        #pragma unroll
        for (int i = 0; i < 4; ++i) {
            float th = tanh_fast(acc[q][i] + b1c[q]);
            int row = rlo + i;
            int idx = ((row << 9) + hcol) ^ ((row & 7) << 3);
            hbuf[idx] = (f16)th;
        }
    }
    __syncthreads();   // BARRIER_B

    // ---- m2: k = h @ W2 + b2 ; W2 regs kt0-10, stream kt11-15 (rolling window) ----
    f32x4 acc2[4];
    #pragma unroll
    for (int t = 0; t < 4; ++t) acc2[t] = (f32x4){0.f, 0.f, 0.f, 0.f};

#define LDW2(KT, T) (*(const f16x8*)(ws + WSO_W2 + ((((KT) * 16 + w * 4 + (T)) << 6) + lane) * 8))
    f16x8 w2s0[4], w2s1[4], w2s2[4];
    #pragma unroll
    for (int t = 0; t < 4; ++t) w2s0[t] = LDW2(11, t);
    #pragma unroll
    for (int t = 0; t < 4; ++t) w2s1[t] = LDW2(12, t);
    #pragma unroll
    for (int t = 0; t < 4; ++t) w2s2[t] = LDW2(13, t);

#define M2STEP(KT, W0, W1_, W2_, W3) { \
        int aidx = ((cn << 9) + (KT) * 32 + koff) ^ ((cn & 7) << 3); \
        f16x8 af = *(const f16x8*)(hbuf + aidx); \
        acc2[0] = MFMA(af, W0,  acc2[0]); \
        acc2[1] = MFMA(af, W1_, acc2[1]); \
        acc2[2] = MFMA(af, W2_, acc2[2]); \
        acc2[3] = MFMA(af, W3,  acc2[3]); }

    #pragma unroll
    for (int kt = 0; kt < 11; ++kt)
        M2STEP(kt, w2r[0][kt], w2r[1][kt], w2r[2][kt], w2r[3][kt]);

    M2STEP(11, w2s0[0], w2s0[1], w2s0[2], w2s0[3]);
    #pragma unroll
    for (int t = 0; t < 4; ++t) w2s0[t] = LDW2(14, t);   // refill
    M2STEP(12, w2s1[0], w2s1[1], w2s1[2], w2s1[3]);
    #pragma unroll
    for (int t = 0; t < 4; ++t) w2s1[t] = LDW2(15, t);   // refill
    M2STEP(13, w2s2[0], w2s2[1], w2s2[2], w2s2[3]);
    M2STEP(14, w2s0[0], w2s0[1], w2s0[2], w2s0[3]);
    M2STEP(15, w2s1[0], w2s1[1], w2s1[2], w2s1[3]);
#undef M2STEP
#undef LDW2

    #pragma unroll
    for (int t = 0; t < 4; ++t)
        #pragma unroll
        for (int i = 0; i < 4; ++i)
            kv[t][i] = acc2[t][i] + b2c[t];
}

__launch_bounds__(256, 1)
__attribute__((amdgpu_waves_per_eu(1, 1)))
__global__ void ode_main(const float* __restrict__ x0, const float* __restrict__ tg,
                         const float* __restrict__ b1, const float* __restrict__ b2,
                         const float* __restrict__ bc1, const float* __restrict__ bc2,
                         const f16* __restrict__ ws, float* __restrict__ out) {
    extern __shared__ char smem[];
    f16* w1lds = (f16*)(smem + LDS_W1);
    f16* yst   = (f16*)(smem + LDS_YST);
    f16* hbuf  = (f16*)(smem + LDS_HB);

    const int tid  = threadIdx.x;
    const int lane = tid & 63;
    const int w    = tid >> 6;            // wave 0..3
    const int r0   = blockIdx.x * 16;
    const int cn   = lane & 15;
    const int rlo  = (lane >> 4) << 2;

    // ---- one-time: fill W1 kt4..7 into LDS (frag-linear copy, 128 KB) ----
    #pragma unroll
    for (int u = 0; u < 32; ++u) {
        int e = (u * 256 + tid) * 8;
        *(f16x8*)(w1lds + e) = *(const f16x8*)(ws + WSO_W1 + 65536 + e);
    }

    // ---- one-time: register-resident weight fragments ----
    f16x8 w1r[8][3];
    #pragma unroll
    for (int q = 0; q < 8; ++q)
        #pragma unroll
        for (int kt = 0; kt < 3; ++kt)
            w1r[q][kt] = *(const f16x8*)(ws + WSO_W1 + (((kt * 32 + w * 8 + q) << 6) + lane) * 8);

    f16x8 w2r[4][11];
    #pragma unroll
    for (int t = 0; t < 4; ++t)
        #pragma unroll
        for (int kt = 0; kt < 11; ++kt)
            w2r[t][kt] = *(const f16x8*)(ws + WSO_W2 + (((kt * 16 + w * 4 + t) << 6) + lane) * 8);

    float b1c[8], b2c[4];
    #pragma unroll
    for (int q = 0; q < 8; ++q) b1c[q] = b1[((w * 8 + q) << 4) + cn];
    #pragma unroll
    for (int t = 0; t < 4; ++t) b2c[t] = b2[((w * 4 + t) << 4) + cn];

    // state: row = r0 + rlo + i, col = (w*4+t)*16 + cn
    float y[4][4];
    #pragma unroll
    for (int t = 0; t < 4; ++t)
        #pragma unroll
        for (int i = 0; i < 4; ++i)
            y[t][i] = x0[(r0 + rlo + i) * DIM + ((w * 4 + t) << 4) + cn];

    __syncthreads();  // LDS W1 fill visible

    float k1[4][4], k2[4][4], k3[4][4], k4[4][4], k5[4][4], k6[4][4];
    float dt = 0.f;

    for (int s = 0; s < 28; ++s) {
        if ((s & 3) == 0) { int iv = s >> 2; dt = (tg[iv + 1] - tg[iv]) * 0.25f; }

        feval([&](int t, int i) { return y[t][i]; },
              k1, ws, w1lds, yst, hbuf, w1r, w2r, lane, w, b1c, b2c);
        feval([&](int t, int i) { return y[t][i] + dt * 0.2f * k1[t][i]; },
              k2, ws, w1lds, yst, hbuf, w1r, w2r, lane, w, b1c, b2c);
        feval([&](int t, int i) { return y[t][i] + dt * (0.075f * k1[t][i] + 0.225f * k2[t][i]); },
              k3, ws, w1lds, yst, hbuf, w1r, w2r, lane, w, b1c, b2c);
        feval([&](int t, int i) { return y[t][i] + dt * ((44.f/45.f) * k1[t][i] + (-56.f/15.f) * k2[t][i]
                                                        + (32.f/9.f) * k3[t][i]); },
              k4, ws, w1lds, yst, hbuf, w1r, w2r, lane, w, b1c, b2c);
        feval([&](int t, int i) { return y[t][i] + dt * ((19372.f/6561.f) * k1[t][i] + (-25360.f/2187.f) * k2[t][i]
                                                        + (64448.f/6561.f) * k3[t][i] + (-212.f/729.f) * k4[t][i]); },
              k5, ws, w1lds, yst, hbuf, w1r, w2r, lane, w, b1c, b2c);
        feval([&](int t, int i) { return y[t][i] + dt * ((9017.f/3168.f) * k1[t][i] + (-355.f/33.f) * k2[t][i]
                                                        + (46732.f/5247.f) * k3[t][i] + (49.f/176.f) * k4[t][i]
                                                        + (-5103.f/18656.f) * k5[t][i]); },
              k6, ws, w1lds, yst, hbuf, w1r, w2r, lane, w, b1c, b2c);

        #pragma unroll
        for (int t = 0; t < 4; ++t)
            #pragma unroll
            for (int i = 0; i < 4; ++i)
                y[t][i] += dt * ((35.f/384.f)   * k1[t][i] + (500.f/1113.f)  * k3[t][i]
                               + (125.f/192.f)  * k4[t][i] + (-2187.f/6784.f) * k5[t][i]
                               + (11.f/84.f)    * k6[t][i]);
    }

    // ---------------- classifier head ----------------
    #pragma unroll
    for (int t = 0; t < 4; ++t)
        #pragma unroll
        for (int i = 0; i < 4; ++i) {
            int row = rlo + i;
            int col = ((w * 4 + t) << 4) + cn;
            int idx = ((row << 8) + col) ^ ((row & 7) << 3);
            yst[idx] = (f16)y[t][i];
        }
    __syncthreads();

    // h1 = relu(y @ Wc1 + bc1): wave w does n-tile w (16 cols of 64)
    {
        const int koff = (lane >> 4) << 3;
        f32x4 ha = (f32x4){0.f, 0.f, 0.f, 0.f};
        #pragma unroll
        for (int kt = 0; kt < 8; ++kt) {
            int aidx = ((cn << 8) + kt * 32 + koff) ^ ((cn & 7) << 3);
            f16x8 af = *(const f16x8*)(yst + aidx);
            f16x8 wf = *(const f16x8*)(ws + WSO_WC1 + (((kt * 4 + w) << 6) + lane) * 8);
            ha = MFMA(af, wf, ha);
        }
        float bb = bc1[(w << 4) + cn];
        #pragma unroll
        for (int i = 0; i < 4; ++i) {
            float v = fmaxf(ha[i] + bb, 0.f);
            int row = rlo + i;
            int idx = ((row << 6) + (w << 4) + cn) ^ ((row & 7) << 3);
            hbuf[idx] = (f16)v;     // h1 lives in hbuf region [16][64]
        }
    }
    __syncthreads();

    // logits = h1 @ Wc2 + bc2 (packed cols 10..15 are zero): wave 0
    if (w == 0) {
        const int koff = (lane >> 4) << 3;
        f32x4 acc = (f32x4){0.f, 0.f, 0.f, 0.f};
        #pragma unroll
        for (int kt = 0; kt < 2; ++kt) {
            int aidx = ((cn << 6) + kt * 32 + koff) ^ ((cn & 7) << 3);
            f16x8 af = *(const f16x8*)(hbuf + aidx);
            f16x8 wf = *(const f16x8*)(ws + WSO_WC2 + ((kt << 6) + lane) * 8);
            acc = MFMA(af, wf, acc);
        }
        if (cn < 10) {
            float bb = bc2[cn];
            #pragma unroll
            for (int i = 0; i < 4; ++i)
                out[(r0 + rlo + i) * 10 + cn] = acc[i] + bb;
        }
    }
}

extern "C" void kernel_launch(void* const* d_in, const int* in_sizes, int n_in,
                              void* d_out, int out_size, void* d_ws, size_t ws_size,
                              hipStream_t stream) {
    const float* x0  = (const float*)d_in[0];
    const float* tg  = (const float*)d_in[1];
    const float* W1  = (const float*)d_in[2];
    const float* b1  = (const float*)d_in[3];
    const float* W2  = (const float*)d_in[4];
    const float* b2  = (const float*)d_in[5];
    const float* Wc1 = (const float*)d_in[6];
    const float* bc1 = (const float*)d_in[7];
    const float* Wc2 = (const float*)d_in[8];
    const float* bc2 = (const float*)d_in[9];
    f16* ws = (f16*)d_ws;
    float* out = (float*)d_out;

    hipFuncSetAttribute((const void*)ode_main,
                        hipFuncAttributeMaxDynamicSharedMemorySize, SMEM_BYTES);

    pack_weights<<<(PACK_TOTAL + 255) / 256, 256, 0, stream>>>(W1, W2, Wc1, Wc2, ws);
    ode_main<<<128, 256, SMEM_BYTES, stream>>>(x0, tg, b1, b2, bc1, bc2, ws, out);
}

// Round 4
// 1675.840 us; speedup vs baseline: 1.3791x; 1.2528x over previous
//
#include <hip/hip_runtime.h>

typedef _Float16 f16;
typedef _Float16 f16x8 __attribute__((ext_vector_type(8)));
typedef float f32x4 __attribute__((ext_vector_type(4)));

#define DIM 256
#define HID 512

// ws element offsets (f16 units)
#define WSO_W1  0
#define WSO_W2  131072
#define WSO_WC1 262144
#define WSO_WC2 278528
#define PACK_TOTAL 279552

// LDS byte layout (dynamic smem): W1 kt4..7 frags | yst | hbuf(+h1)
#define LDS_W1   0
#define LDS_YST  131072
#define LDS_HB   139264
#define SMEM_BYTES 155648   // 152 KB -> 1 block/CU

#define MFMA(a, b, c) __builtin_amdgcn_mfma_f32_16x16x32_f16(a, b, c, 0, 0, 0)

// Pack weights into MFMA B-fragment order (16x16x32_f16):
// frag (kt,nt): lane l, elem j -> B[k = kt*32 + (l>>4)*8 + j][n = nt*16 + (l&15)]
__global__ void pack_weights(const float* __restrict__ W1, const float* __restrict__ W2,
                             const float* __restrict__ Wc1, const float* __restrict__ Wc2,
                             f16* __restrict__ ws) {
    int gid = blockIdx.x * 256 + threadIdx.x;
    if (gid >= PACK_TOTAL) return;
    if (gid < WSO_W2) {
        int g = gid;
        int j = g & 7, lane = (g >> 3) & 63, fi = g >> 9;
        int kt = fi >> 5, nt = fi & 31;                 // 8 x 32 frags
        int k = kt * 32 + ((lane >> 4) << 3) + j;
        int n = (nt << 4) + (lane & 15);
        ws[WSO_W1 + g] = (f16)W1[k * HID + n];
    } else if (gid < WSO_WC1) {
        int g = gid - WSO_W2;
        int j = g & 7, lane = (g >> 3) & 63, fi = g >> 9;
        int kt = fi >> 4, nt = fi & 15;                 // 16 x 16 frags
        int k = kt * 32 + ((lane >> 4) << 3) + j;
        int n = (nt << 4) + (lane & 15);
        ws[WSO_W2 + g] = (f16)W2[k * DIM + n];
    } else if (gid < WSO_WC2) {
        int g = gid - WSO_WC1;
        int j = g & 7, lane = (g >> 3) & 63, fi = g >> 9;
        int kt = fi >> 2, nt = fi & 3;                  // 8 x 4 frags
        int k = kt * 32 + ((lane >> 4) << 3) + j;
        int n = (nt << 4) + (lane & 15);
        ws[WSO_WC1 + g] = (f16)Wc1[k * 64 + n];
    } else {
        int g = gid - WSO_WC2;
        int j = g & 7, lane = (g >> 3) & 63, kt = g >> 9; // 2 frags
        int k = kt * 32 + ((lane >> 4) << 3) + j;
        int n = lane & 15;
        ws[WSO_WC2 + g] = (n < 10) ? (f16)Wc2[k * 10 + n] : (f16)0.0f;
    }
}

__device__ __forceinline__ float tanh_fast(float x) {
    float e = __expf(2.0f * x);
    return 1.0f - 2.0f * __builtin_amdgcn_rcpf(e + 1.0f);
}

// f(ys) = tanh(ys@W1+b1)@W2+b2 for the block's 16 rows. 8 waves.
// Wave w: m1 n-tiles 4w..4w+3 (HID), m2 n-tiles 2w,2w+1 (DIM).
// Thread slot layout: row = (lane>>4)*4+i ; col = w*32 + t*16 + (lane&15), t in 0..1
// FIN(t,i) -> stage input element; FOUT(t,i,v) consumes k element.
template <class FIN, class FOUT>
__device__ __forceinline__ void feval(FIN yin, FOUT kout,
        const f16* __restrict__ ws, const f16* w1lds, f16* yst, f16* hbuf,
        const f16x8 (&w1r)[4][3], const f16x8 (&w2r)[2][8],
        int lane, int w, const float b1c[4], const float b2c[2]) {
    const int cn   = lane & 15;
    const int rlo  = (lane >> 4) << 2;
    const int koff = (lane >> 4) << 3;

#define LDW1(KT, Q) (*(const f16x8*)(ws + WSO_W1 + ((((KT) * 32 + 4 * w + (Q)) << 9) + lane * 8)))
#define LDW2(KT, T) (*(const f16x8*)(ws + WSO_W2 + ((((KT) * 16 + 2 * w + (T)) << 9) + lane * 8)))

    // ---- issue all streamed loads up front (consumed late; L2-resident) ----
    f16x8 w1s[4];
    #pragma unroll
    for (int q = 0; q < 4; ++q) w1s[q] = LDW1(3, q);
    f16x8 w2s[4][2];
    #pragma unroll
    for (int st = 0; st < 4; ++st) {
        w2s[st][0] = LDW2(8 + st, 0);
        w2s[st][1] = LDW2(8 + st, 1);
    }

    // ---- write stage input, swizzled f16 [16][256] ----
    #pragma unroll
    for (int t = 0; t < 2; ++t)
        #pragma unroll
        for (int i = 0; i < 4; ++i) {
            int row = rlo + i;
            int col = w * 32 + t * 16 + cn;
            int idx = ((row << 8) + col) ^ ((row & 7) << 3);
            yst[idx] = (f16)yin(t, i);
        }
    __syncthreads();   // BARRIER_A

    // ---- m1: h = ys @ W1 ; kt order {0,1,2,4,5,6,7,3} (streamed kt3 last) ----
    f32x4 acc[4];
    #pragma unroll
    for (int q = 0; q < 4; ++q) acc[q] = (f32x4){0.f, 0.f, 0.f, 0.f};
    const int kord[8] = {0, 1, 2, 4, 5, 6, 7, 3};
    #pragma unroll
    for (int s = 0; s < 8; ++s) {
        const int kt = kord[s];
        int aidx = ((cn << 8) + kt * 32 + koff) ^ ((cn & 7) << 3);
        f16x8 af = *(const f16x8*)(yst + aidx);
        #pragma unroll
        for (int q = 0; q < 4; ++q) {
            f16x8 wf;
            if (kt < 3)       wf = w1r[q][kt];
            else if (kt == 3) wf = w1s[q];
            else              wf = *(const f16x8*)(w1lds + (((kt - 4) * 32 + 4 * w + q) << 9) + lane * 8);
            acc[q] = MFMA(af, wf, acc[q]);
        }
    }
    // tanh -> swizzled hbuf [16][512]
    #pragma unroll
    for (int q = 0; q < 4; ++q) {
        int hcol = ((4 * w + q) << 4) + cn;
        #pragma unroll
        for (int i = 0; i < 4; ++i) {
            float th = tanh_fast(acc[q][i] + b1c[q]);
            int row = rlo + i;
            int idx = ((row << 9) + hcol) ^ ((row & 7) << 3);
            hbuf[idx] = (f16)th;
        }
    }
    __syncthreads();   // BARRIER_B

    // ---- m2: k = h @ W2 + b2 ; order [8..11, 0..3, 12..15, 4..7] so refills have lead ----
    f32x4 acc2[2];
    acc2[0] = (f32x4){0.f, 0.f, 0.f, 0.f};
    acc2[1] = (f32x4){0.f, 0.f, 0.f, 0.f};

#define M2STEP(KT, B0, B1) { \
        int aidx = ((cn << 9) + (KT) * 32 + koff) ^ ((cn & 7) << 3); \
        f16x8 af = *(const f16x8*)(hbuf + aidx); \
        acc2[0] = MFMA(af, B0, acc2[0]); \
        acc2[1] = MFMA(af, B1, acc2[1]); }

    #pragma unroll
    for (int st = 0; st < 4; ++st) {
        M2STEP(8 + st, w2s[st][0], w2s[st][1]);
        w2s[st][0] = LDW2(12 + st, 0);          // refill; consumed 8 steps later
        w2s[st][1] = LDW2(12 + st, 1);
    }
    #pragma unroll
    for (int kt = 0; kt < 4; ++kt) M2STEP(kt, w2r[0][kt], w2r[1][kt]);
    #pragma unroll
    for (int st = 0; st < 4; ++st) M2STEP(12 + st, w2s[st][0], w2s[st][1]);
    #pragma unroll
    for (int kt = 4; kt < 8; ++kt) M2STEP(kt, w2r[0][kt], w2r[1][kt]);
#undef M2STEP
#undef LDW1
#undef LDW2

    #pragma unroll
    for (int t = 0; t < 2; ++t)
        #pragma unroll
        for (int i = 0; i < 4; ++i)
            kout(t, i, acc2[t][i] + b2c[t]);
}

__launch_bounds__(512, 2)
__global__ void ode_main(const float* __restrict__ x0, const float* __restrict__ tg,
                         const float* __restrict__ b1, const float* __restrict__ b2,
                         const float* __restrict__ bc1, const float* __restrict__ bc2,
                         const f16* __restrict__ ws, float* __restrict__ out) {
    extern __shared__ char smem[];
    f16* w1lds = (f16*)(smem + LDS_W1);
    f16* yst   = (f16*)(smem + LDS_YST);
    f16* hbuf  = (f16*)(smem + LDS_HB);

    const int tid  = threadIdx.x;
    const int lane = tid & 63;
    const int w    = tid >> 6;            // wave 0..7
    const int r0   = blockIdx.x * 16;
    const int cn   = lane & 15;
    const int rlo  = (lane >> 4) << 2;

    // ---- one-time: W1 kt4..7 into LDS (frag-linear, 128 KB) ----
    #pragma unroll
    for (int u = 0; u < 16; ++u) {
        int e = (u * 512 + tid) * 8;
        *(f16x8*)(w1lds + e) = *(const f16x8*)(ws + WSO_W1 + 65536 + e);
    }

    // ---- one-time: register-resident weight fragments ----
    f16x8 w1r[4][3];
    #pragma unroll
    for (int q = 0; q < 4; ++q)
        #pragma unroll
        for (int kt = 0; kt < 3; ++kt)
            w1r[q][kt] = *(const f16x8*)(ws + WSO_W1 + (((kt * 32 + 4 * w + q) << 9) + lane * 8));

    f16x8 w2r[2][8];
    #pragma unroll
    for (int t = 0; t < 2; ++t)
        #pragma unroll
        for (int kt = 0; kt < 8; ++kt)
            w2r[t][kt] = *(const f16x8*)(ws + WSO_W2 + (((kt * 16 + 2 * w + t) << 9) + lane * 8));

    float b1c[4], b2c[2];
    #pragma unroll
    for (int q = 0; q < 4; ++q) b1c[q] = b1[((4 * w + q) << 4) + cn];
    #pragma unroll
    for (int t = 0; t < 2; ++t) b2c[t] = b2[((2 * w + t) << 4) + cn];

    // state: row = r0 + rlo + i, col = w*32 + t*16 + cn
    float y[2][4];
    #pragma unroll
    for (int t = 0; t < 2; ++t)
        #pragma unroll
        for (int i = 0; i < 4; ++i)
            y[t][i] = x0[(r0 + rlo + i) * DIM + w * 32 + t * 16 + cn];

    __syncthreads();  // W1 LDS fill visible

    float k1[2][4], k2[2][4], k3[2][4], k4[2][4], k5[2][4];
    float dt = 0.f;

    for (int s = 0; s < 28; ++s) {
        if ((s & 3) == 0) { int iv = s >> 2; dt = (tg[iv + 1] - tg[iv]) * 0.25f; }

        feval([&](int t, int i) { return y[t][i]; },
              [&](int t, int i, float v) { k1[t][i] = v; },
              ws, w1lds, yst, hbuf, w1r, w2r, lane, w, b1c, b2c);
        feval([&](int t, int i) { return y[t][i] + dt * 0.2f * k1[t][i]; },
              [&](int t, int i, float v) { k2[t][i] = v; },
              ws, w1lds, yst, hbuf, w1r, w2r, lane, w, b1c, b2c);
        feval([&](int t, int i) { return y[t][i] + dt * (0.075f * k1[t][i] + 0.225f * k2[t][i]); },
              [&](int t, int i, float v) { k3[t][i] = v; },
              ws, w1lds, yst, hbuf, w1r, w2r, lane, w, b1c, b2c);
        feval([&](int t, int i) { return y[t][i] + dt * ((44.f/45.f) * k1[t][i] + (-56.f/15.f) * k2[t][i]
                                                        + (32.f/9.f) * k3[t][i]); },
              [&](int t, int i, float v) { k4[t][i] = v; },
              ws, w1lds, yst, hbuf, w1r, w2r, lane, w, b1c, b2c);
        feval([&](int t, int i) { return y[t][i] + dt * ((19372.f/6561.f) * k1[t][i] + (-25360.f/2187.f) * k2[t][i]
                                                        + (64448.f/6561.f) * k3[t][i] + (-212.f/729.f) * k4[t][i]); },
              [&](int t, int i, float v) { k5[t][i] = v; },
              ws, w1lds, yst, hbuf, w1r, w2r, lane, w, b1c, b2c);
        // stage 6: fold k6 straight into y (k6 never stored)
        feval([&](int t, int i) { return y[t][i] + dt * ((9017.f/3168.f) * k1[t][i] + (-355.f/33.f) * k2[t][i]
                                                        + (46732.f/5247.f) * k3[t][i] + (49.f/176.f) * k4[t][i]
                                                        + (-5103.f/18656.f) * k5[t][i]); },
              [&](int t, int i, float v) {
                  y[t][i] += dt * ((35.f/384.f)    * k1[t][i] + (500.f/1113.f)  * k3[t][i]
                                 + (125.f/192.f)   * k4[t][i] + (-2187.f/6784.f) * k5[t][i]
                                 + (11.f/84.f)     * v);
              },
              ws, w1lds, yst, hbuf, w1r, w2r, lane, w, b1c, b2c);
    }

    // ---------------- classifier head ----------------
    #pragma unroll
    for (int t = 0; t < 2; ++t)
        #pragma unroll
        for (int i = 0; i < 4; ++i) {
            int row = rlo + i;
            int col = w * 32 + t * 16 + cn;
            int idx = ((row << 8) + col) ^ ((row & 7) << 3);
            yst[idx] = (f16)y[t][i];
        }
    __syncthreads();

    // h1 = relu(y @ Wc1 + bc1): waves 0..3, one 16-col tile each; h1 in hbuf[0..1K)
    if (w < 4) {
        const int koff = (lane >> 4) << 3;
        f32x4 ha = (f32x4){0.f, 0.f, 0.f, 0.f};
        #pragma unroll
        for (int kt = 0; kt < 8; ++kt) {
            int aidx = ((cn << 8) + kt * 32 + koff) ^ ((cn & 7) << 3);
            f16x8 af = *(const f16x8*)(yst + aidx);
            f16x8 wf = *(const f16x8*)(ws + WSO_WC1 + (((kt * 4 + w) << 9) + lane * 8));
            ha = MFMA(af, wf, ha);
        }
        float bb = bc1[(w << 4) + cn];
        #pragma unroll
        for (int i = 0; i < 4; ++i) {
            float v = fmaxf(ha[i] + bb, 0.f);
            int row = rlo + i;
            int idx = ((row << 6) + (w << 4) + cn) ^ ((row & 7) << 3);
            hbuf[idx] = (f16)v;
        }
    }
    __syncthreads();

    // logits = h1 @ Wc2 + bc2 (packed cols 10..15 zero): wave 0
    if (w == 0) {
        const int koff = (lane >> 4) << 3;
        f32x4 acc = (f32x4){0.f, 0.f, 0.f, 0.f};
        #pragma unroll
        for (int kt = 0; kt < 2; ++kt) {
            int aidx = ((cn << 6) + kt * 32 + koff) ^ ((cn & 7) << 3);
            f16x8 af = *(const f16x8*)(hbuf + aidx);
            f16x8 wf = *(const f16x8*)(ws + WSO_WC2 + ((kt << 9) + lane * 8));
            acc = MFMA(af, wf, acc);
        }
        if (cn < 10) {
            float bb = bc2[cn];
            #pragma unroll
            for (int i = 0; i < 4; ++i)
                out[(r0 + rlo + i) * 10 + cn] = acc[i] + bb;
        }
    }
}

extern "C" void kernel_launch(void* const* d_in, const int* in_sizes, int n_in,
                              void* d_out, int out_size, void* d_ws, size_t ws_size,
                              hipStream_t stream) {
    const float* x0  = (const float*)d_in[0];
    const float* tg  = (const float*)d_in[1];
    const float* W1  = (const float*)d_in[2];
    const float* b1  = (const float*)d_in[3];
    const float* W2  = (const float*)d_in[4];
    const float* b2  = (const float*)d_in[5];
    const float* Wc1 = (const float*)d_in[6];
    const float* bc1 = (const float*)d_in[7];
    const float* Wc2 = (const float*)d_in[8];
    const float* bc2 = (const float*)d_in[9];
    f16* ws = (f16*)d_ws;
    float* out = (float*)d_out;

    hipFuncSetAttribute((const void*)ode_main,
                        hipFuncAttributeMaxDynamicSharedMemorySize, SMEM_BYTES);

    pack_weights<<<(PACK_TOTAL + 255) / 256, 256, 0, stream>>>(W1, W2, Wc1, Wc2, ws);
    ode_main<<<128, 512, SMEM_BYTES, stream>>>(x0, tg, b1, b2, bc1, bc2, ws, out);
}